// Round 17
// baseline (77.422 us; speedup 1.0000x reference)
//
#include <hip/hip_runtime.h>

#define T_LEN 192

// ===========================================================================
// ---- tiled GEMM body v3: Y[n,o,t] = sum_c W[o,c]*X[c,t] + B[o] ------------
// TRANSX=false: X[c,t] = Xg[(n*cstr + c)*192 + t]
// TRANSX=true : X[c,u] = Xg[(n*192 + u)*192 + c]   (At layout, transposed)
// Tile 32(o) x 64(t) x 64(c); 256 thr; micro 2o x 4t; register prefetch.
// LDS tiles XOR-swizzled (col' = col ^ 4*((row>>2)&7)) -> conflict-free.
// ===========================================================================
template<bool TRANSX>
__device__ __forceinline__ void gemm_body(
    float* smem,
    const float* __restrict__ W, const float* __restrict__ B,
    const float* __restrict__ X, float* __restrict__ Y,
    int cin, int cstr, int ostr, int wnstr,
    int t0, int o0, int n, int tid)
{
  float* Ws = smem;                                  // [64][32] swizzled
  float (*Xs)[68] = (float(*)[68])(smem + 2048);     // [64][68] swizzled
  const int to = tid >> 4, tt = tid & 15;
  float acc[2][4] = {};

  auto loadW = [&](int l, int c0) {
    int idx = l * 256 + tid; int rr = idx >> 4, c4 = idx & 15;
    return *reinterpret_cast<const float4*>(
        &W[(size_t)n * wnstr + (size_t)(o0 + rr) * cin + c0 + c4 * 4]);
  };
  auto loadX = [&](int l, int c0) {
    int idx = l * 256 + tid; int rr = idx >> 4, c4 = idx & 15;
    if (!TRANSX)
      return *reinterpret_cast<const float4*>(
          &X[((size_t)n * cstr + c0 + rr) * T_LEN + t0 + c4 * 4]);
    else
      return *reinterpret_cast<const float4*>(
          &X[((size_t)n * 192 + t0 + rr) * 192 + c0 + c4 * 4]);
  };

  float4 wreg[2], xreg[4];
#pragma unroll
  for (int l = 0; l < 2; ++l) wreg[l] = loadW(l, 0);
#pragma unroll
  for (int l = 0; l < 4; ++l) xreg[l] = loadX(l, 0);

  for (int c0 = 0; c0 < cin; c0 += 64) {
    __syncthreads();
#pragma unroll
    for (int l = 0; l < 2; ++l) {
      int idx = l * 256 + tid;
      int rr = idx >> 4, c4 = idx & 15;
      float4 wv = wreg[l];
      const int sw = 4 * (c4 & 7);
      Ws[(c4 * 4 + 0) * 32 + (rr ^ sw)] = wv.x;
      Ws[(c4 * 4 + 1) * 32 + (rr ^ sw)] = wv.y;
      Ws[(c4 * 4 + 2) * 32 + (rr ^ sw)] = wv.z;
      Ws[(c4 * 4 + 3) * 32 + (rr ^ sw)] = wv.w;
    }
#pragma unroll
    for (int l = 0; l < 4; ++l) {
      int idx = l * 256 + tid;
      int rr = idx >> 4, c4 = idx & 15;
      if (!TRANSX) {
        *reinterpret_cast<float4*>(
            &Xs[rr][(c4 * 4) ^ (4 * ((rr >> 2) & 7))]) = xreg[l];
      } else {
        float4 xv = xreg[l];
        const int sw = 4 * (c4 & 7);
        Xs[c4 * 4 + 0][rr ^ sw] = xv.x;
        Xs[c4 * 4 + 1][rr ^ sw] = xv.y;
        Xs[c4 * 4 + 2][rr ^ sw] = xv.z;
        Xs[c4 * 4 + 3][rr ^ sw] = xv.w;
      }
    }
    if (c0 + 64 < cin) {
#pragma unroll
      for (int l = 0; l < 2; ++l) wreg[l] = loadW(l, c0 + 64);
#pragma unroll
      for (int l = 0; l < 4; ++l) xreg[l] = loadX(l, c0 + 64);
    }
    __syncthreads();
#pragma unroll
    for (int kk = 0; kk < 64; ++kk) {
      const int sw = 4 * ((kk >> 2) & 7);
      float2 a = *reinterpret_cast<const float2*>(
          &Ws[kk * 32 + ((to * 2) ^ sw)]);
      float4 b = *reinterpret_cast<const float4*>(
          &Xs[kk][(tt * 4) ^ sw]);
      acc[0][0] += a.x * b.x; acc[0][1] += a.x * b.y;
      acc[0][2] += a.x * b.z; acc[0][3] += a.x * b.w;
      acc[1][0] += a.y * b.x; acc[1][1] += a.y * b.y;
      acc[1][2] += a.y * b.z; acc[1][3] += a.y * b.w;
    }
  }
#pragma unroll
  for (int i = 0; i < 2; ++i) {
    float bi = B ? B[o0 + to * 2 + i] : 0.f;
    float4 v = make_float4(acc[i][0] + bi, acc[i][1] + bi,
                           acc[i][2] + bi, acc[i][3] + bi);
    *reinterpret_cast<float4*>(
        &Y[((size_t)n * ostr + o0 + to * 2 + i) * T_LEN + t0 + tt * 4]) = v;
  }
}

// ===========================================================================
// foldA: parts[chunk][j*K+i][c'] = sum_{c in 16-chunk} wa[c,j]*wk[c,c',i]
// Barrier-free: thread = c' (256), block = (s, chunk of 16 c, j-group).
// ===========================================================================
template<int K, int JN>
__device__ __forceinline__ void foldA_body(
    const float* __restrict__ wa, const float* __restrict__ wk,
    float* __restrict__ parts, int j0, int chunk, int tid)
{
  float acc[JN][K];
#pragma unroll
  for (int jj = 0; jj < JN; ++jj)
#pragma unroll
    for (int i = 0; i < K; ++i) acc[jj][i] = 0.f;

  const int c0 = chunk * 16;
  for (int c = c0; c < c0 + 16; ++c) {
    const float* base = &wk[((size_t)c * 256 + tid) * K];
    float v[K];
#pragma unroll
    for (int i = 0; i < K; ++i) v[i] = base[i];
    float w[JN];
#pragma unroll
    for (int jj = 0; jj < JN; ++jj) w[jj] = wa[c * K + j0 + jj];
#pragma unroll
    for (int jj = 0; jj < JN; ++jj)
#pragma unroll
      for (int i = 0; i < K; ++i) acc[jj][i] += w[jj] * v[i];
  }
#pragma unroll
  for (int jj = 0; jj < JN; ++jj)
#pragma unroll
    for (int i = 0; i < K; ++i)
      parts[((size_t)chunk * K * K + (j0 + jj) * K + i) * 256 + tid] = acc[jj][i];
}

// ---- cka[s,j] = sum_c wa[c,j]*bk[c] ---------------------------------------
__device__ __forceinline__ void cka_body(
    const float* __restrict__ wa0, const float* __restrict__ bk0,
    const float* __restrict__ wa1, const float* __restrict__ bk1,
    const float* __restrict__ wa2, const float* __restrict__ bk2,
    float* __restrict__ cka, int tid)
{
  if (tid >= 21) return;
  int s, j, K; const float *wa, *bk;
  if (tid < 3)       { s = 0; j = tid;      K = 3;  wa = wa0; bk = bk0; }
  else if (tid < 10) { s = 1; j = tid - 3;  K = 7;  wa = wa1; bk = bk1; }
  else               { s = 2; j = tid - 10; K = 11; wa = wa2; bk = bk2; }
  float acc = 0.f;
  for (int c = 0; c < 128; ++c) acc += wa[c * K + j] * bk[c];
  cka[s * 11 + j] = acc;
}

// ===========================================================================
// foldB: stage chunk-summed WKA row in LDS, then coalesced wp GEMV.
// half==0 block also computes bpA[ji] via LDS dot.
// ===========================================================================
template<int K>
__device__ __forceinline__ void foldB_body(
    float* lds, const float* __restrict__ parts, const float* __restrict__ wp,
    const float* __restrict__ bp, float* __restrict__ wxas,
    float* __restrict__ bpA_s, int ji, int half, int tid)
{
  constexpr int KP = (K + 3) & ~3;
  constexpr int K2 = K * K;
  float s = 0.f;
#pragma unroll
  for (int ch = 0; ch < 8; ++ch)
    s += parts[((size_t)(ch * K2 + ji)) * 256 + tid];
  lds[tid] = s;
  __syncthreads();

  const int cin = half * 256 + tid;
  float acc = 0.f;
  for (int c = 0; c < 256; ++c)
    acc += lds[c] * wp[(size_t)c * 512 + cin];
  const int j = ji / K, i = ji - j * K;
  wxas[(size_t)cin * K * KP + i * KP + j] = acc;

  if (half == 0 && tid == 0) {
    float b = 0.f;
    for (int c = 0; c < 256; ++c) b += lds[c] * bp[c];
    bpA_s[j * 11 + i] = b;
  }
}

// ===========================================================================
// rcomp: rpart[n,cc,j,t] = sum_{16ch,i} WXA[c,i,j]*xpad[n,c,t+i-A]
// ===========================================================================
template<int A>
__device__ __forceinline__ void rcomp_body(
    float* smem, const float* __restrict__ x, const float* __restrict__ WXAs,
    float* __restrict__ rps, int cc, int n, int tid)
{
  constexpr int K  = 2 * A + 1;
  constexpr int KP = (K + 3) & ~3;
  constexpr int WH = 192 + 2 * A;
  constexpr int WS = 204;
  float* Xs = smem;               // 16 x 204
  float* Wl = smem + 16 * WS;     // 16 x K x KP
  const int c0 = cc * 16;

  for (int idx = tid; idx < 16 * WH; idx += 256) {
    int c = idx / WH, p = idx - c * WH;
    int tau = p - A;
    Xs[c * WS + p] = (tau >= 0 && tau < 192)
        ? x[((size_t)n * 512 + c0 + c) * 192 + tau] : 0.f;
  }
  {
    const float4* wg = reinterpret_cast<const float4*>(WXAs + (size_t)c0 * K * KP);
    float4* wl = reinterpret_cast<float4*>(Wl);
    for (int idx = tid; idx < 16 * K * KP / 4; idx += 256) wl[idx] = wg[idx];
  }
  __syncthreads();

  const int w = tid >> 6, lane = tid & 63;
  const int csub = lane >> 4, tpos = lane & 15;
  const int tb = w * 48 + tpos * 3;

  float acc[K][3];
#pragma unroll
  for (int j = 0; j < K; ++j) { acc[j][0] = 0.f; acc[j][1] = 0.f; acc[j][2] = 0.f; }

#pragma unroll
  for (int c = 0; c < 4; ++c) {
    const int ch = csub * 4 + c;
    float win[K + 2];
#pragma unroll
    for (int p = 0; p < K + 2; ++p) win[p] = Xs[ch * WS + tb + p];
    const float* wr = &Wl[ch * K * KP];
#pragma unroll
    for (int i = 0; i < K; ++i) {
#pragma unroll
      for (int j = 0; j < K; ++j) {
        float wv = wr[i * KP + j];
        acc[j][0] += wv * win[i + 0];
        acc[j][1] += wv * win[i + 1];
        acc[j][2] += wv * win[i + 2];
      }
    }
  }
#pragma unroll
  for (int j = 0; j < K; ++j) {
#pragma unroll
    for (int q = 0; q < 3; ++q) {
      float v = acc[j][q];
      v += __shfl_xor(v, 16);
      v += __shfl_xor(v, 32);
      acc[j][q] = v;
    }
  }
  if (csub == 0) {
#pragma unroll
    for (int j = 0; j < K; ++j) {
      float* dst = &rps[(((size_t)n * 32 + cc) * K + j) * 192 + tb];
      dst[0] = acc[j][0]; dst[1] = acc[j][1]; dst[2] = acc[j][2];
    }
  }
}

// ---- rreduce: rbuf[s,n,j,t] = sum_cc rpart + cka + boundary bp term -------
__device__ __forceinline__ void rreduce_body(
    const float* __restrict__ rpart, const float* __restrict__ cka,
    const float* __restrict__ bpA, float* __restrict__ rbuf,
    int n, int sj, int t)
{
  if (t >= 192) return;
  const int s = sj < 3 ? 0 : sj < 10 ? 1 : 2;
  const int j = sj < 3 ? sj : sj < 10 ? sj - 3 : sj - 10;
  const int A = (s == 0) ? 1 : (s == 1) ? 3 : 5;
  const int K = 2 * A + 1;
  const int roff = (s == 0) ? 0 : (s == 1) ? 147456 : 491520;
  const float* rp = rpart + roff;
  float acc = cka[s * 11 + j];
#pragma unroll 8
  for (int cc = 0; cc < 32; ++cc)
    acc += rp[(((size_t)n * 32 + cc) * K + j) * 192 + t];
  for (int i = 0; i < K; ++i) {
    int tau = t + i - A;
    if (tau >= 0 && tau < 192) acc += bpA[s * 121 + j * 11 + i];
  }
  rbuf[((size_t)(s * 8 + n) * 11 + j) * 192 + t] = acc;
}

// ===========================================================================
// abuild: 1 wave = 1 softmax column u; 64 lanes x 3 t; shfl-only
// ===========================================================================
template<int A>
__device__ __forceinline__ float gather_val(const float* __restrict__ rs,
                                            int t, int u)
{
  constexpr int K = 2 * A + 1;
  float val = 0.f;
#pragma unroll
  for (int j = 0; j < K; ++j) {
    int tp = t + j - A;
    int d = tp - u;
    if (tp >= 0 && tp < 192 && d <= A && d >= -A) val += rs[j * 192 + tp];
  }
  return val;
}

__device__ __forceinline__ void abuild_body(
    const float* __restrict__ rbuf,
    const float* __restrict__ ba0, const float* __restrict__ ba1,
    const float* __restrict__ ba2, float* __restrict__ At,
    int ublk, int n, int tid)
{
  const int w = tid >> 6, lane = tid & 63;
  const int u = ublk * 4 + w;
  const int t0 = lane * 3;
  const float* r0 = rbuf + (size_t)(0 * 8 + n) * 11 * 192;
  const float* r1 = rbuf + (size_t)(1 * 8 + n) * 11 * 192;
  const float* r2 = rbuf + (size_t)(2 * 8 + n) * 11 * 192;
  float v0[3], v1[3], v2[3];
  const float b0 = ba0[0], b1 = ba1[0], b2 = ba2[0];
#pragma unroll
  for (int q = 0; q < 3; ++q) {
    v0[q] = b0 + gather_val<1>(r0, t0 + q, u);
    v1[q] = b1 + gather_val<3>(r1, t0 + q, u);
    v2[q] = b2 + gather_val<5>(r2, t0 + q, u);
  }
  float m0 = fmaxf(fmaxf(v0[0], v0[1]), v0[2]);
  float m1 = fmaxf(fmaxf(v1[0], v1[1]), v1[2]);
  float m2 = fmaxf(fmaxf(v2[0], v2[1]), v2[2]);
#pragma unroll
  for (int off = 32; off > 0; off >>= 1) {
    m0 = fmaxf(m0, __shfl_xor(m0, off));
    m1 = fmaxf(m1, __shfl_xor(m1, off));
    m2 = fmaxf(m2, __shfl_xor(m2, off));
  }
  float e0[3], e1[3], e2[3];
#pragma unroll
  for (int q = 0; q < 3; ++q) {
    e0[q] = __expf(v0[q] - m0);
    e1[q] = __expf(v1[q] - m1);
    e2[q] = __expf(v2[q] - m2);
  }
  float s0 = e0[0] + e0[1] + e0[2];
  float s1 = e1[0] + e1[1] + e1[2];
  float s2 = e2[0] + e2[1] + e2[2];
#pragma unroll
  for (int off = 32; off > 0; off >>= 1) {
    s0 += __shfl_xor(s0, off);
    s1 += __shfl_xor(s1, off);
    s2 += __shfl_xor(s2, off);
  }
  const float i0 = 1.f / s0, i1 = 1.f / s1, i2 = 1.f / s2;
  float* dst = &At[((size_t)n * 192 + u) * 192 + t0];
#pragma unroll
  for (int q = 0; q < 3; ++q)
    dst[q] = e0[q] * i0 + e1[q] * i1 + e2[q] * i2;
}

// ---- grouped conv (groups=32, K=3) + ReLU ---------------------------------
__device__ __forceinline__ void gconv_body(
    const float* __restrict__ hin, const float* __restrict__ w2,
    const float* __restrict__ b2, float* __restrict__ hout,
    int bx, int by, int n, int tid)
{
  const int t  = (tid & 63) + bx * 64;
  const int oc = (tid >> 6) + by * 4;
  const int g  = oc >> 3;
  float acc = b2[oc];
  for (int i = 0; i < 8; ++i) {
    const float* hrow = &hin[((size_t)n * 512 + g * 8 + i) * 192];
#pragma unroll
    for (int j = 0; j < 3; ++j) {
      int tt = t + j - 1;
      float hv = (tt >= 0 && tt < 192) ? hrow[tt] : 0.f;
      acc += w2[((size_t)oc * 8 + i) * 3 + j] * hv;
    }
  }
  hout[((size_t)n * 512 + 256 + oc) * 192 + t] = fmaxf(acc, 0.f);
}

// ---- At[n][u][t] -> Aout[n][t][u] ------------------------------------------
__device__ __forceinline__ void transpose_body(
    float* smem, const float* __restrict__ At, float* __restrict__ Aout,
    int bx, int by, int n, int tid)
{
  float (*tile)[33] = (float(*)[33])smem;
  const int xx = tid & 31, y = tid >> 5;
  for (int yy = y; yy < 32; yy += 8)
    tile[yy][xx] = At[((size_t)n * 192 + by * 32 + yy) * 192 + bx * 32 + xx];
  __syncthreads();
  for (int yy = y; yy < 32; yy += 8)
    Aout[((size_t)n * 192 + bx * 32 + yy) * 192 + by * 32 + xx] = tile[xx][yy];
}

// ===========================================================================
// K1: gemm h1 (192)  ||  foldA (48)  ||  cka (1)   = 241 blocks
// (gemm-h1 depends only on inputs -> moved to level 0 to fill the CUs
//  while foldA's latency-bound loads drain.)
// ===========================================================================
__global__ __launch_bounds__(256) void k1_kernel(
    const float* __restrict__ x, const float* __restrict__ w1,
    const float* __restrict__ b1,
    const float* __restrict__ wa0, const float* __restrict__ wk0,
    const float* __restrict__ bk0,
    const float* __restrict__ wa1, const float* __restrict__ wk1,
    const float* __restrict__ bk1,
    const float* __restrict__ wa2, const float* __restrict__ wk2,
    const float* __restrict__ bk2,
    float* __restrict__ hall, float* __restrict__ partsA,
    float* __restrict__ cka)
{
  __shared__ __align__(16) float smem[6400];
  const int bid = blockIdx.x, tid = threadIdx.x;
  if (bid < 192) {
    const int tx = bid % 3, oy = (bid / 3) % 8, n = bid / 24;
    gemm_body<false>(smem, w1, b1, x, hall, 512, 512, 512, 0,
                     tx * 64, oy * 32, n, tid);
  } else if (bid < 240) {
    const int fbid = bid - 192;           // 0..47
    const int s = fbid >> 4, sub = fbid & 15;
    const int chunk = sub >> 1, jg = sub & 1;
    if (s == 0) {
      if (jg == 0) foldA_body<3, 2>(wa0, wk0, partsA,          0, chunk, tid);
      else         foldA_body<3, 1>(wa0, wk0, partsA,          2, chunk, tid);
    } else if (s == 1) {
      if (jg == 0) foldA_body<7, 4>(wa1, wk1, partsA + 18432,  0, chunk, tid);
      else         foldA_body<7, 3>(wa1, wk1, partsA + 18432,  4, chunk, tid);
    } else {
      if (jg == 0) foldA_body<11, 6>(wa2, wk2, partsA + 118784, 0, chunk, tid);
      else         foldA_body<11, 5>(wa2, wk2, partsA + 118784, 6, chunk, tid);
    }
  } else {
    cka_body(wa0, bk0, wa1, bk1, wa2, bk2, cka, tid);
  }
}

// ===========================================================================
// K2: foldB (358)  ||  gconv (1536)   = 1894 blocks
// (gconv needs only h1 from K1.)
// ===========================================================================
__global__ __launch_bounds__(256) void k2_kernel(
    const float* __restrict__ partsA,
    const float* __restrict__ wp0, const float* __restrict__ bp0,
    const float* __restrict__ wp1, const float* __restrict__ bp1,
    const float* __restrict__ wp2, const float* __restrict__ bp2,
    float* __restrict__ WXA, float* __restrict__ bpA,
    const float* __restrict__ w2, const float* __restrict__ b2,
    float* __restrict__ hall)
{
  __shared__ float lds[256];
  const int bid = blockIdx.x, tid = threadIdx.x;
  if (bid < 18)
    foldB_body<3>(lds, partsA, wp0, bp0, WXA, bpA,
                  bid >> 1, bid & 1, tid);
  else if (bid < 116)
    foldB_body<7>(lds, partsA + 18432, wp1, bp1, WXA + 6144, bpA + 121,
                  (bid - 18) >> 1, (bid - 18) & 1, tid);
  else if (bid < 358)
    foldB_body<11>(lds, partsA + 118784, wp2, bp2, WXA + 34816, bpA + 242,
                   (bid - 116) >> 1, (bid - 116) & 1, tid);
  else {
    const int gid = bid - 358;
    gconv_body(hall, w2, b2, hall, gid % 3, (gid / 3) % 64, gid / 192, tid);
  }
}

// ===========================================================================
// K3: rcomp (768)  ||  gemm w3 (192)   = 960 blocks
// (w3-gemm needs only h2 from K2's gconv.)
// ===========================================================================
__global__ __launch_bounds__(256) void k3_kernel(
    const float* __restrict__ x, const float* __restrict__ WXA,
    float* __restrict__ rpart,
    const float* __restrict__ hall, const float* __restrict__ w3,
    const float* __restrict__ b3, float* __restrict__ xs)
{
  __shared__ __align__(16) float smem[6400];
  const int bid = blockIdx.x, tid = threadIdx.x;
  if (bid < 768) {
    const int cc = bid % 32, n = (bid / 32) % 8, s = bid / 256;
    if (s == 0)      rcomp_body<1>(smem, x, WXA,         rpart,          cc, n, tid);
    else if (s == 1) rcomp_body<3>(smem, x, WXA + 6144,  rpart + 147456, cc, n, tid);
    else             rcomp_body<5>(smem, x, WXA + 34816, rpart + 491520, cc, n, tid);
  } else {
    const int gid = bid - 768;
    const int tx = gid % 3, oy = (gid / 3) % 8, n = gid / 24;
    gemm_body<false>(smem, w3, b3, hall + 256 * 192, xs, 256, 512, 256, 0,
                     tx * 64, oy * 32, n, tid);
  }
}

// ===========================================================================
// K4: rreduce (168)
// ===========================================================================
__global__ __launch_bounds__(192) void k4_kernel(
    const float* __restrict__ rpart, const float* __restrict__ cka,
    const float* __restrict__ bpA, float* __restrict__ rbuf)
{
  rreduce_body(rpart, cka, bpA, rbuf, blockIdx.x % 8, blockIdx.x / 8,
               threadIdx.x);
}

// ===========================================================================
// K5: abuild (384)
// ===========================================================================
__global__ __launch_bounds__(256) void k5_kernel(
    const float* __restrict__ rbuf,
    const float* __restrict__ ba0, const float* __restrict__ ba1,
    const float* __restrict__ ba2, float* __restrict__ At)
{
  abuild_body(rbuf, ba0, ba1, ba2, At, blockIdx.x % 48, blockIdx.x / 48,
              threadIdx.x);
}

// ===========================================================================
// K6: out0 = xs@A (192, At read transposed)  ||  transpose (288)  = 480
// ===========================================================================
__global__ __launch_bounds__(256) void k6_kernel(
    const float* __restrict__ xs, const float* __restrict__ At,
    float* __restrict__ out0, float* __restrict__ Aout)
{
  __shared__ __align__(16) float smem[6400];
  const int bid = blockIdx.x, tid = threadIdx.x;
  if (bid < 192) {
    const int tx = bid % 3, oy = (bid / 3) % 8, n = bid / 24;
    gemm_body<true>(smem, xs, nullptr, At, out0, 192, 0, 256, 256 * 192,
                    tx * 64, oy * 32, n, tid);
  } else {
    const int gid = bid - 192;
    transpose_body(smem, At, Aout, gid % 6, (gid / 6) % 6, gid / 36, tid);
  }
}

// ===========================================================================
extern "C" void kernel_launch(void* const* d_in, const int* in_sizes, int n_in,
                              void* d_out, int out_size, void* d_ws, size_t ws_size,
                              hipStream_t stream)
{
  const float* x   = (const float*)d_in[0];
  const float* wp0 = (const float*)d_in[1];
  const float* bp0 = (const float*)d_in[2];
  const float* wk0 = (const float*)d_in[3];
  const float* bk0 = (const float*)d_in[4];
  const float* wa0 = (const float*)d_in[5];
  const float* ba0 = (const float*)d_in[6];
  const float* wp1 = (const float*)d_in[7];
  const float* bp1 = (const float*)d_in[8];
  const float* wk1 = (const float*)d_in[9];
  const float* bk1 = (const float*)d_in[10];
  const float* wa1 = (const float*)d_in[11];
  const float* ba1 = (const float*)d_in[12];
  const float* wp2 = (const float*)d_in[13];
  const float* bp2 = (const float*)d_in[14];
  const float* wk2 = (const float*)d_in[15];
  const float* bk2 = (const float*)d_in[16];
  const float* wa2 = (const float*)d_in[17];
  const float* ba2 = (const float*)d_in[18];
  const float* w1  = (const float*)d_in[19];
  const float* b1  = (const float*)d_in[20];
  const float* w2  = (const float*)d_in[21];
  const float* b2  = (const float*)d_in[22];
  const float* w3  = (const float*)d_in[23];
  const float* b3  = (const float*)d_in[24];

  float* ws     = (float*)d_ws;
  float* hall   = ws;                         // [8][512][192]        =   786,432
  float* At     = hall   + 786432;            // [8][192][192]        =   294,912
  float* xs     = At     + 294912;            // [8][256][192]        =   393,216
  float* rpart  = xs     + 393216;            // [8][32][3+7+11][192] = 1,032,192
  float* rbuf   = rpart  + 1032192;           // [3][8][11][192]      =    50,688
  float* WXA    = rbuf   + 50688;             // [512]*(12+56+132)    =   102,400
  float* bpA    = WXA    + 102400;            // [3][121]             =       384
  float* cka    = bpA    + 384;               // [3][11] (pad 64)     =        64
  float* partsA = cka    + 64;                // 8*(9+49+121)*256     =   366,592
  float* out0   = (float*)d_out;              // [8][256][192]
  float* Aout   = out0 + 8 * 256 * 192;       // [8][192][192]

  // K1: h1 = w1@x  ||  foldA partial WKA  ||  cka
  k1_kernel<<<241, 256, 0, stream>>>(
      x, w1, b1, wa0, wk0, bk0, wa1, wk1, bk1, wa2, wk2, bk2,
      hall, partsA, cka);

  // K2: foldB -> WXA, bpA  ||  grouped conv + relu (h1 -> h2)
  k2_kernel<<<358 + 1536, 256, 0, stream>>>(
      partsA, wp0, bp0, wp1, bp1, wp2, bp2, WXA, bpA, w2, b2, hall);

  // K3: banded rcomp on x  ||  xs = w3@h2
  k3_kernel<<<768 + 192, 256, 0, stream>>>(x, WXA, rpart, hall, w3, b3, xs);

  // K4: rreduce -> rbuf
  k4_kernel<<<168, 192, 0, stream>>>(rpart, cka, bpA, rbuf);

  // K5: softmax A-build (wave-per-column) -> At
  k5_kernel<<<384, 256, 0, stream>>>(rbuf, ba0, ba1, ba2, At);

  // K6: out0 = xs@A (transposed At staging)  ||  Aout = At^T
  k6_kernel<<<192 + 288, 256, 0, stream>>>(xs, At, out0, Aout);
}

// Round 18
// 71.293 us; speedup vs baseline: 1.0860x; 1.0860x over previous
//
#include <hip/hip_runtime.h>

#define T_LEN 192

// ===========================================================================
// ---- tiled GEMM body v3: Y[n,o,t] = sum_c W[o,c]*X[c,t] + B[o] ------------
// TRANSX=false: X[c,t] = Xg[(n*cstr + c)*192 + t]
// TRANSX=true : X[c,u] = Xg[(n*192 + u)*192 + c]   (At layout, transposed)
// Tile 32(o) x 64(t) x 64(c); 256 thr; micro 2o x 4t; register prefetch.
// LDS tiles XOR-swizzled (col' = col ^ 4*((row>>2)&7)) -> conflict-free
// scatter stores (old layout was ~8-way conflicted: 2.75M cycles in R12 p1).
// ===========================================================================
template<bool TRANSX>
__device__ __forceinline__ void gemm_body(
    float* smem,
    const float* __restrict__ W, const float* __restrict__ B,
    const float* __restrict__ X, float* __restrict__ Y,
    int cin, int cstr, int ostr, int wnstr,
    int t0, int o0, int n, int tid)
{
  float* Ws = smem;                                  // [64][32] swizzled
  float (*Xs)[68] = (float(*)[68])(smem + 2048);     // [64][68] swizzled
  const int to = tid >> 4, tt = tid & 15;
  float acc[2][4] = {};

  auto loadW = [&](int l, int c0) {
    int idx = l * 256 + tid; int rr = idx >> 4, c4 = idx & 15;
    return *reinterpret_cast<const float4*>(
        &W[(size_t)n * wnstr + (size_t)(o0 + rr) * cin + c0 + c4 * 4]);
  };
  auto loadX = [&](int l, int c0) {
    int idx = l * 256 + tid; int rr = idx >> 4, c4 = idx & 15;
    if (!TRANSX)
      return *reinterpret_cast<const float4*>(
          &X[((size_t)n * cstr + c0 + rr) * T_LEN + t0 + c4 * 4]);
    else
      return *reinterpret_cast<const float4*>(
          &X[((size_t)n * 192 + t0 + rr) * 192 + c0 + c4 * 4]);
  };

  float4 wreg[2], xreg[4];
#pragma unroll
  for (int l = 0; l < 2; ++l) wreg[l] = loadW(l, 0);
#pragma unroll
  for (int l = 0; l < 4; ++l) xreg[l] = loadX(l, 0);

  for (int c0 = 0; c0 < cin; c0 += 64) {
    __syncthreads();     // previous compute done reading LDS
    // ---- stage W: [c][o] scatter, swizzled ----
#pragma unroll
    for (int l = 0; l < 2; ++l) {
      int idx = l * 256 + tid;
      int rr = idx >> 4, c4 = idx & 15;          // rr = o-local, c4 = c-group
      float4 wv = wreg[l];
      const int sw = 4 * (c4 & 7);
      Ws[(c4 * 4 + 0) * 32 + (rr ^ sw)] = wv.x;
      Ws[(c4 * 4 + 1) * 32 + (rr ^ sw)] = wv.y;
      Ws[(c4 * 4 + 2) * 32 + (rr ^ sw)] = wv.z;
      Ws[(c4 * 4 + 3) * 32 + (rr ^ sw)] = wv.w;
    }
    // ---- stage X: [c][t], swizzled ----
#pragma unroll
    for (int l = 0; l < 4; ++l) {
      int idx = l * 256 + tid;
      int rr = idx >> 4, c4 = idx & 15;
      if (!TRANSX) {                              // rr = c, c4 = t-group
        *reinterpret_cast<float4*>(
            &Xs[rr][(c4 * 4) ^ (4 * ((rr >> 2) & 7))]) = xreg[l];
      } else {                                    // rr = t, c4 = c-group
        float4 xv = xreg[l];
        const int sw = 4 * (c4 & 7);
        Xs[c4 * 4 + 0][rr ^ sw] = xv.x;
        Xs[c4 * 4 + 1][rr ^ sw] = xv.y;
        Xs[c4 * 4 + 2][rr ^ sw] = xv.z;
        Xs[c4 * 4 + 3][rr ^ sw] = xv.w;
      }
    }
    if (c0 + 64 < cin) {   // prefetch next tile into registers
#pragma unroll
      for (int l = 0; l < 2; ++l) wreg[l] = loadW(l, c0 + 64);
#pragma unroll
      for (int l = 0; l < 4; ++l) xreg[l] = loadX(l, c0 + 64);
    }
    __syncthreads();
#pragma unroll
    for (int kk = 0; kk < 64; ++kk) {
      const int sw = 4 * ((kk >> 2) & 7);
      float2 a = *reinterpret_cast<const float2*>(
          &Ws[kk * 32 + ((to * 2) ^ sw)]);
      float4 b = *reinterpret_cast<const float4*>(
          &Xs[kk][(tt * 4) ^ sw]);
      acc[0][0] += a.x * b.x; acc[0][1] += a.x * b.y;
      acc[0][2] += a.x * b.z; acc[0][3] += a.x * b.w;
      acc[1][0] += a.y * b.x; acc[1][1] += a.y * b.y;
      acc[1][2] += a.y * b.z; acc[1][3] += a.y * b.w;
    }
  }
#pragma unroll
  for (int i = 0; i < 2; ++i) {
    float bi = B ? B[o0 + to * 2 + i] : 0.f;
    float4 v = make_float4(acc[i][0] + bi, acc[i][1] + bi,
                           acc[i][2] + bi, acc[i][3] + bi);
    *reinterpret_cast<float4*>(
        &Y[((size_t)n * ostr + o0 + to * 2 + i) * T_LEN + t0 + tt * 4]) = v;
  }
}

// ===========================================================================
// foldA: parts[chunk][j*K+i][c'] = sum_{c in 16-chunk} wa[c,j]*wk[c,c',i]
// Barrier-free: thread = c' (256), block = (s, chunk of 16 c, j-group).
// ===========================================================================
template<int K, int JN>
__device__ __forceinline__ void foldA_body(
    const float* __restrict__ wa, const float* __restrict__ wk,
    float* __restrict__ parts, int j0, int chunk, int tid)
{
  float acc[JN][K];
#pragma unroll
  for (int jj = 0; jj < JN; ++jj)
#pragma unroll
    for (int i = 0; i < K; ++i) acc[jj][i] = 0.f;

  const int c0 = chunk * 16;
  for (int c = c0; c < c0 + 16; ++c) {
    const float* base = &wk[((size_t)c * 256 + tid) * K];
    float v[K];
#pragma unroll
    for (int i = 0; i < K; ++i) v[i] = base[i];
    float w[JN];
#pragma unroll
    for (int jj = 0; jj < JN; ++jj) w[jj] = wa[c * K + j0 + jj];
#pragma unroll
    for (int jj = 0; jj < JN; ++jj)
#pragma unroll
      for (int i = 0; i < K; ++i) acc[jj][i] += w[jj] * v[i];
  }
#pragma unroll
  for (int jj = 0; jj < JN; ++jj)
#pragma unroll
    for (int i = 0; i < K; ++i)
      parts[((size_t)chunk * K * K + (j0 + jj) * K + i) * 256 + tid] = acc[jj][i];
}

// ---- cka[s,j] = sum_c wa[c,j]*bk[c] ---------------------------------------
__device__ __forceinline__ void cka_body(
    const float* __restrict__ wa0, const float* __restrict__ bk0,
    const float* __restrict__ wa1, const float* __restrict__ bk1,
    const float* __restrict__ wa2, const float* __restrict__ bk2,
    float* __restrict__ cka, int tid)
{
  if (tid >= 21) return;
  int s, j, K; const float *wa, *bk;
  if (tid < 3)       { s = 0; j = tid;      K = 3;  wa = wa0; bk = bk0; }
  else if (tid < 10) { s = 1; j = tid - 3;  K = 7;  wa = wa1; bk = bk1; }
  else               { s = 2; j = tid - 10; K = 11; wa = wa2; bk = bk2; }
  float acc = 0.f;
  for (int c = 0; c < 128; ++c) acc += wa[c * K + j] * bk[c];
  cka[s * 11 + j] = acc;
}

// ===========================================================================
// foldB: stage chunk-summed WKA row in LDS, then coalesced wp GEMV.
// half==0 block also computes bpA[ji] via LDS dot.
// ===========================================================================
template<int K>
__device__ __forceinline__ void foldB_body(
    float* lds, const float* __restrict__ parts, const float* __restrict__ wp,
    const float* __restrict__ bp, float* __restrict__ wxas,
    float* __restrict__ bpA_s, int ji, int half, int tid)
{
  constexpr int KP = (K + 3) & ~3;
  constexpr int K2 = K * K;
  float s = 0.f;
#pragma unroll
  for (int ch = 0; ch < 8; ++ch)
    s += parts[((size_t)(ch * K2 + ji)) * 256 + tid];
  lds[tid] = s;
  __syncthreads();

  const int cin = half * 256 + tid;
  float acc = 0.f;
  for (int c = 0; c < 256; ++c)
    acc += lds[c] * wp[(size_t)c * 512 + cin];
  const int j = ji / K, i = ji - j * K;
  wxas[(size_t)cin * K * KP + i * KP + j] = acc;

  if (half == 0 && tid == 0) {
    float b = 0.f;
    for (int c = 0; c < 256; ++c) b += lds[c] * bp[c];
    bpA_s[j * 11 + i] = b;
  }
}

// ===========================================================================
// rcomp: rpart[n,cc,j,t] = sum_{16ch,i} WXA[c,i,j]*xpad[n,c,t+i-A]
// ===========================================================================
template<int A>
__device__ __forceinline__ void rcomp_body(
    float* smem, const float* __restrict__ x, const float* __restrict__ WXAs,
    float* __restrict__ rps, int cc, int n, int tid)
{
  constexpr int K  = 2 * A + 1;
  constexpr int KP = (K + 3) & ~3;
  constexpr int WH = 192 + 2 * A;
  constexpr int WS = 204;
  float* Xs = smem;               // 16 x 204
  float* Wl = smem + 16 * WS;     // 16 x K x KP
  const int c0 = cc * 16;

  for (int idx = tid; idx < 16 * WH; idx += 256) {
    int c = idx / WH, p = idx - c * WH;
    int tau = p - A;
    Xs[c * WS + p] = (tau >= 0 && tau < 192)
        ? x[((size_t)n * 512 + c0 + c) * 192 + tau] : 0.f;
  }
  {
    const float4* wg = reinterpret_cast<const float4*>(WXAs + (size_t)c0 * K * KP);
    float4* wl = reinterpret_cast<float4*>(Wl);
    for (int idx = tid; idx < 16 * K * KP / 4; idx += 256) wl[idx] = wg[idx];
  }
  __syncthreads();

  const int w = tid >> 6, lane = tid & 63;
  const int csub = lane >> 4, tpos = lane & 15;
  const int tb = w * 48 + tpos * 3;

  float acc[K][3];
#pragma unroll
  for (int j = 0; j < K; ++j) { acc[j][0] = 0.f; acc[j][1] = 0.f; acc[j][2] = 0.f; }

#pragma unroll
  for (int c = 0; c < 4; ++c) {
    const int ch = csub * 4 + c;
    float win[K + 2];
#pragma unroll
    for (int p = 0; p < K + 2; ++p) win[p] = Xs[ch * WS + tb + p];
    const float* wr = &Wl[ch * K * KP];
#pragma unroll
    for (int i = 0; i < K; ++i) {
#pragma unroll
      for (int j = 0; j < K; ++j) {
        float wv = wr[i * KP + j];
        acc[j][0] += wv * win[i + 0];
        acc[j][1] += wv * win[i + 1];
        acc[j][2] += wv * win[i + 2];
      }
    }
  }
#pragma unroll
  for (int j = 0; j < K; ++j) {
#pragma unroll
    for (int q = 0; q < 3; ++q) {
      float v = acc[j][q];
      v += __shfl_xor(v, 16);
      v += __shfl_xor(v, 32);
      acc[j][q] = v;
    }
  }
  if (csub == 0) {
#pragma unroll
    for (int j = 0; j < K; ++j) {
      float* dst = &rps[(((size_t)n * 32 + cc) * K + j) * 192 + tb];
      dst[0] = acc[j][0]; dst[1] = acc[j][1]; dst[2] = acc[j][2];
    }
  }
}

// ---- rreduce: rbuf[s,n,j,t] = sum_cc rpart + cka + boundary bp term -------
__device__ __forceinline__ void rreduce_body(
    const float* __restrict__ rpart, const float* __restrict__ cka,
    const float* __restrict__ bpA, float* __restrict__ rbuf,
    int n, int sj, int t)
{
  if (t >= 192) return;
  const int s = sj < 3 ? 0 : sj < 10 ? 1 : 2;
  const int j = sj < 3 ? sj : sj < 10 ? sj - 3 : sj - 10;
  const int A = (s == 0) ? 1 : (s == 1) ? 3 : 5;
  const int K = 2 * A + 1;
  const int roff = (s == 0) ? 0 : (s == 1) ? 147456 : 491520;
  const float* rp = rpart + roff;
  float acc = cka[s * 11 + j];
#pragma unroll 8
  for (int cc = 0; cc < 32; ++cc)
    acc += rp[(((size_t)n * 32 + cc) * K + j) * 192 + t];
  for (int i = 0; i < K; ++i) {
    int tau = t + i - A;
    if (tau >= 0 && tau < 192) acc += bpA[s * 121 + j * 11 + i];
  }
  rbuf[((size_t)(s * 8 + n) * 11 + j) * 192 + t] = acc;
}

// ===========================================================================
// abuild: 1 wave = 1 softmax column u; 64 lanes x 3 t; shfl-only
// ===========================================================================
template<int A>
__device__ __forceinline__ float gather_val(const float* __restrict__ rs,
                                            int t, int u)
{
  constexpr int K = 2 * A + 1;
  float val = 0.f;
#pragma unroll
  for (int j = 0; j < K; ++j) {
    int tp = t + j - A;
    int d = tp - u;
    if (tp >= 0 && tp < 192 && d <= A && d >= -A) val += rs[j * 192 + tp];
  }
  return val;
}

__device__ __forceinline__ void abuild_body(
    const float* __restrict__ rbuf,
    const float* __restrict__ ba0, const float* __restrict__ ba1,
    const float* __restrict__ ba2, float* __restrict__ At,
    int ublk, int n, int tid)
{
  const int w = tid >> 6, lane = tid & 63;
  const int u = ublk * 4 + w;
  const int t0 = lane * 3;
  const float* r0 = rbuf + (size_t)(0 * 8 + n) * 11 * 192;
  const float* r1 = rbuf + (size_t)(1 * 8 + n) * 11 * 192;
  const float* r2 = rbuf + (size_t)(2 * 8 + n) * 11 * 192;
  float v0[3], v1[3], v2[3];
  const float b0 = ba0[0], b1 = ba1[0], b2 = ba2[0];
#pragma unroll
  for (int q = 0; q < 3; ++q) {
    v0[q] = b0 + gather_val<1>(r0, t0 + q, u);
    v1[q] = b1 + gather_val<3>(r1, t0 + q, u);
    v2[q] = b2 + gather_val<5>(r2, t0 + q, u);
  }
  float m0 = fmaxf(fmaxf(v0[0], v0[1]), v0[2]);
  float m1 = fmaxf(fmaxf(v1[0], v1[1]), v1[2]);
  float m2 = fmaxf(fmaxf(v2[0], v2[1]), v2[2]);
#pragma unroll
  for (int off = 32; off > 0; off >>= 1) {
    m0 = fmaxf(m0, __shfl_xor(m0, off));
    m1 = fmaxf(m1, __shfl_xor(m1, off));
    m2 = fmaxf(m2, __shfl_xor(m2, off));
  }
  float e0[3], e1[3], e2[3];
#pragma unroll
  for (int q = 0; q < 3; ++q) {
    e0[q] = __expf(v0[q] - m0);
    e1[q] = __expf(v1[q] - m1);
    e2[q] = __expf(v2[q] - m2);
  }
  float s0 = e0[0] + e0[1] + e0[2];
  float s1 = e1[0] + e1[1] + e1[2];
  float s2 = e2[0] + e2[1] + e2[2];
#pragma unroll
  for (int off = 32; off > 0; off >>= 1) {
    s0 += __shfl_xor(s0, off);
    s1 += __shfl_xor(s1, off);
    s2 += __shfl_xor(s2, off);
  }
  const float i0 = 1.f / s0, i1 = 1.f / s1, i2 = 1.f / s2;
  float* dst = &At[((size_t)n * 192 + u) * 192 + t0];
#pragma unroll
  for (int q = 0; q < 3; ++q)
    dst[q] = e0[q] * i0 + e1[q] * i1 + e2[q] * i2;
}

// ---- grouped conv (groups=32, K=3) + ReLU ---------------------------------
__device__ __forceinline__ void gconv_body(
    const float* __restrict__ hin, const float* __restrict__ w2,
    const float* __restrict__ b2, float* __restrict__ hout,
    int bx, int by, int n, int tid)
{
  const int t  = (tid & 63) + bx * 64;
  const int oc = (tid >> 6) + by * 4;
  const int g  = oc >> 3;
  float acc = b2[oc];
  for (int i = 0; i < 8; ++i) {
    const float* hrow = &hin[((size_t)n * 512 + g * 8 + i) * 192];
#pragma unroll
    for (int j = 0; j < 3; ++j) {
      int tt = t + j - 1;
      float hv = (tt >= 0 && tt < 192) ? hrow[tt] : 0.f;
      acc += w2[((size_t)oc * 8 + i) * 3 + j] * hv;
    }
  }
  hout[((size_t)n * 512 + 256 + oc) * 192 + t] = fmaxf(acc, 0.f);
}

// ---- At[n][u][t] -> Aout[n][t][u] ------------------------------------------
__device__ __forceinline__ void transpose_body(
    float* smem, const float* __restrict__ At, float* __restrict__ Aout,
    int bx, int by, int n, int tid)
{
  float (*tile)[33] = (float(*)[33])smem;
  const int xx = tid & 31, y = tid >> 5;
  for (int yy = y; yy < 32; yy += 8)
    tile[yy][xx] = At[((size_t)n * 192 + by * 32 + yy) * 192 + bx * 32 + xx];
  __syncthreads();
  for (int yy = y; yy < 32; yy += 8)
    Aout[((size_t)n * 192 + bx * 32 + yy) * 192 + by * 32 + xx] = tile[xx][yy];
}

// ===========================================================================
// K0a: foldA (48) + cka (1)
// ===========================================================================
__global__ __launch_bounds__(256) void fold_a(
    const float* __restrict__ wa0, const float* __restrict__ wk0,
    const float* __restrict__ bk0,
    const float* __restrict__ wa1, const float* __restrict__ wk1,
    const float* __restrict__ bk1,
    const float* __restrict__ wa2, const float* __restrict__ wk2,
    const float* __restrict__ bk2,
    float* __restrict__ partsA, float* __restrict__ cka)
{
  const int bid = blockIdx.x, tid = threadIdx.x;
  if (bid < 48) {
    const int s = bid >> 4, sub = bid & 15;
    const int chunk = sub >> 1, jg = sub & 1;
    if (s == 0) {
      if (jg == 0) foldA_body<3, 2>(wa0, wk0, partsA,          0, chunk, tid);
      else         foldA_body<3, 1>(wa0, wk0, partsA,          2, chunk, tid);
    } else if (s == 1) {
      if (jg == 0) foldA_body<7, 4>(wa1, wk1, partsA + 18432,  0, chunk, tid);
      else         foldA_body<7, 3>(wa1, wk1, partsA + 18432,  4, chunk, tid);
    } else {
      if (jg == 0) foldA_body<11, 6>(wa2, wk2, partsA + 118784, 0, chunk, tid);
      else         foldA_body<11, 5>(wa2, wk2, partsA + 118784, 6, chunk, tid);
    }
  } else {
    cka_body(wa0, bk0, wa1, bk1, wa2, bk2, cka, tid);
  }
}

// ===========================================================================
// K0b: foldB (358) — LDS-staged WKA row; bpA inline in half==0 blocks
// ===========================================================================
__global__ __launch_bounds__(256) void fold_b(
    const float* __restrict__ partsA,
    const float* __restrict__ wp0, const float* __restrict__ bp0,
    const float* __restrict__ wp1, const float* __restrict__ bp1,
    const float* __restrict__ wp2, const float* __restrict__ bp2,
    float* __restrict__ WXA, float* __restrict__ bpA)
{
  __shared__ float lds[256];
  const int bid = blockIdx.x, tid = threadIdx.x;
  if (bid < 18)
    foldB_body<3>(lds, partsA, wp0, bp0, WXA, bpA,
                  bid >> 1, bid & 1, tid);
  else if (bid < 116)
    foldB_body<7>(lds, partsA + 18432, wp1, bp1, WXA + 6144, bpA + 121,
                  (bid - 18) >> 1, (bid - 18) & 1, tid);
  else
    foldB_body<11>(lds, partsA + 118784, wp2, bp2, WXA + 34816, bpA + 242,
                   (bid - 116) >> 1, (bid - 116) & 1, tid);
}

// ===========================================================================
// K2: gemm h1 (192)  ||  rcomp (768)
// ===========================================================================
__global__ __launch_bounds__(256) void k2_kernel(
    const float* __restrict__ x, const float* __restrict__ w1,
    const float* __restrict__ b1, const float* __restrict__ WXA,
    float* __restrict__ hall, float* __restrict__ rpart)
{
  __shared__ __align__(16) float smem[6400];
  const int bid = blockIdx.x, tid = threadIdx.x;
  if (bid < 192) {
    const int tx = bid % 3, oy = (bid / 3) % 8, n = bid / 24;
    gemm_body<false>(smem, w1, b1, x, hall, 512, 512, 512, 0,
                     tx * 64, oy * 32, n, tid);
  } else {
    const int rid = bid - 192;
    const int cc = rid % 32, n = (rid / 32) % 8, s = rid / 256;
    if (s == 0)      rcomp_body<1>(smem, x, WXA,         rpart,          cc, n, tid);
    else if (s == 1) rcomp_body<3>(smem, x, WXA + 6144,  rpart + 147456, cc, n, tid);
    else             rcomp_body<5>(smem, x, WXA + 34816, rpart + 491520, cc, n, tid);
  }
}

// ===========================================================================
// K3: rreduce (168)  ||  gconv (1536)
// ===========================================================================
__global__ __launch_bounds__(256) void k3_kernel(
    const float* __restrict__ rpart, const float* __restrict__ cka,
    const float* __restrict__ bpA, float* __restrict__ rbuf,
    const float* __restrict__ w2, const float* __restrict__ b2,
    float* __restrict__ hall)
{
  const int bid = blockIdx.x, tid = threadIdx.x;
  if (bid < 168) {
    rreduce_body(rpart, cka, bpA, rbuf, bid % 8, bid / 8, tid);
  } else {
    const int gid = bid - 168;
    gconv_body(hall, w2, b2, hall, gid % 3, (gid / 3) % 64, gid / 192, tid);
  }
}

// ===========================================================================
// K4: abuild (384)  ||  gemm w3 (192)
// ===========================================================================
__global__ __launch_bounds__(256) void k4_kernel(
    const float* __restrict__ rbuf,
    const float* __restrict__ ba0, const float* __restrict__ ba1,
    const float* __restrict__ ba2, float* __restrict__ At,
    const float* __restrict__ hall, const float* __restrict__ w3,
    const float* __restrict__ b3, float* __restrict__ xs)
{
  __shared__ __align__(16) float smem[6400];
  const int bid = blockIdx.x, tid = threadIdx.x;
  if (bid < 384) {
    abuild_body(rbuf, ba0, ba1, ba2, At, bid % 48, bid / 48, tid);
  } else {
    const int gid = bid - 384;
    const int tx = gid % 3, oy = (gid / 3) % 8, n = gid / 24;
    gemm_body<false>(smem, w3, b3, hall + 256 * 192, xs, 256, 512, 256, 0,
                     tx * 64, oy * 32, n, tid);
  }
}

// ===========================================================================
// K5: out0 = xs@A (192, At read transposed)  ||  transpose (288)
// ===========================================================================
__global__ __launch_bounds__(256) void k5_kernel(
    const float* __restrict__ xs, const float* __restrict__ At,
    float* __restrict__ out0, float* __restrict__ Aout)
{
  __shared__ __align__(16) float smem[6400];
  const int bid = blockIdx.x, tid = threadIdx.x;
  if (bid < 192) {
    const int tx = bid % 3, oy = (bid / 3) % 8, n = bid / 24;
    gemm_body<true>(smem, xs, nullptr, At, out0, 192, 0, 256, 256 * 192,
                    tx * 64, oy * 32, n, tid);
  } else {
    const int gid = bid - 192;
    transpose_body(smem, At, Aout, gid % 6, (gid / 6) % 6, gid / 36, tid);
  }
}

// ===========================================================================
extern "C" void kernel_launch(void* const* d_in, const int* in_sizes, int n_in,
                              void* d_out, int out_size, void* d_ws, size_t ws_size,
                              hipStream_t stream)
{
  const float* x   = (const float*)d_in[0];
  const float* wp0 = (const float*)d_in[1];
  const float* bp0 = (const float*)d_in[2];
  const float* wk0 = (const float*)d_in[3];
  const float* bk0 = (const float*)d_in[4];
  const float* wa0 = (const float*)d_in[5];
  const float* ba0 = (const float*)d_in[6];
  const float* wp1 = (const float*)d_in[7];
  const float* bp1 = (const float*)d_in[8];
  const float* wk1 = (const float*)d_in[9];
  const float* bk1 = (const float*)d_in[10];
  const float* wa1 = (const float*)d_in[11];
  const float* ba1 = (const float*)d_in[12];
  const float* wp2 = (const float*)d_in[13];
  const float* bp2 = (const float*)d_in[14];
  const float* wk2 = (const float*)d_in[15];
  const float* bk2 = (const float*)d_in[16];
  const float* wa2 = (const float*)d_in[17];
  const float* ba2 = (const float*)d_in[18];
  const float* w1  = (const float*)d_in[19];
  const float* b1  = (const float*)d_in[20];
  const float* w2  = (const float*)d_in[21];
  const float* b2  = (const float*)d_in[22];
  const float* w3  = (const float*)d_in[23];
  const float* b3  = (const float*)d_in[24];

  float* ws     = (float*)d_ws;
  float* hall   = ws;                         // [8][512][192]        =   786,432
  float* At     = hall   + 786432;            // [8][192][192]        =   294,912
  float* xs     = At     + 294912;            // [8][256][192]        =   393,216
  float* rpart  = xs     + 393216;            // [8][32][3+7+11][192] = 1,032,192
  float* rbuf   = rpart  + 1032192;           // [3][8][11][192]      =    50,688
  float* WXA    = rbuf   + 50688;             // [512]*(12+56+132)    =   102,400
  float* bpA    = WXA    + 102400;            // [3][121]             =       384
  float* cka    = bpA    + 384;               // [3][11] (pad 64)     =        64
  float* partsA = cka    + 64;                // 8*(9+49+121)*256     =   366,592
  float* out0   = (float*)d_out;              // [8][256][192]
  float* Aout   = out0 + 8 * 256 * 192;       // [8][192][192]

  // K0a: foldA partial WKA (barrier-free, coalesced wk)  +  cka
  fold_a<<<49, 256, 0, stream>>>(
      wa0, wk0, bk0, wa1, wk1, bk1, wa2, wk2, bk2, partsA, cka);

  // K0b: foldB -> WXA (LDS-staged row) + bpA
  fold_b<<<358, 256, 0, stream>>>(
      partsA, wp0, bp0, wp1, bp1, wp2, bp2, WXA, bpA);

  // K2: h1 = w1@x  ||  banded rcomp on x
  k2_kernel<<<192 + 768, 256, 0, stream>>>(x, w1, b1, WXA, hall, rpart);

  // K3: rreduce  ||  grouped conv + relu (h1 -> h2)
  k3_kernel<<<168 + 1536, 256, 0, stream>>>(rpart, cka, bpA, rbuf, w2, b2, hall);

  // K4: softmax A-build (wave-per-column)  ||  xs = w3@h2
  k4_kernel<<<384 + 192, 256, 0, stream>>>(rbuf, ba0, ba1, ba2, At,
                                           hall, w3, b3, xs);

  // K5: out0 = xs@A (transposed At staging)  ||  Aout = At^T
  k5_kernel<<<192 + 288, 256, 0, stream>>>(xs, At, out0, Aout);
}